// Round 2
// baseline (10819.286 us; speedup 1.0000x reference)
//
#include <hip/hip_runtime.h>

// LSTM: B=64, S=512, I=H=O=1024.  bf16 MFMA, fp32 accum.
//  - pack_weights: 9x [1024][1024] fp32 -> bf16 transposed/packed panels
//  - convert_x:    x [B][S][I] fp32 -> xT [S][B][I] bf16
//  - lstm_seq:     ONE persistent kernel, 64 blocks x 512 thr, all 512 steps,
//                  custom device-scope grid barrier per step. Fused K=2048
//                  ([h | x_t] @ [W_h ; W_i]), 8-wave split-K, 2-stage LDS
//                  reduce, gate epilogue, c in registers, h double-buffered.
//  - final_gemm:   out = h_T @ W_y (fp32 out)

typedef __bf16 bfv8 __attribute__((ext_vector_type(8)));
typedef float f32x4 __attribute__((ext_vector_type(4)));

__device__ __forceinline__ unsigned short f2bf(float x) {
    union { float f; unsigned int u; } v; v.f = x;
    unsigned int r = (v.u + 0x7FFFu + ((v.u >> 16) & 1u)) >> 16;
    return (unsigned short)r;
}

struct SrcPtrs { const float* p[9]; };

// ---------------------------------------------------------------------------
__global__ __launch_bounds__(256) void pack_weights(SrcPtrs sp,
                                                    unsigned short* __restrict__ Whp,
                                                    unsigned short* __restrict__ Wip,
                                                    unsigned short* __restrict__ Wy) {
    __shared__ float tile[64][65];
    const int z = blockIdx.z;
    const float* __restrict__ src = sp.p[z];
    const int n0 = blockIdx.x * 64, k0 = blockIdx.y * 64;
    const int tc = threadIdx.x & 63, tq = threadIdx.x >> 6;

    #pragma unroll
    for (int r = 0; r < 16; ++r) {
        const int kk = tq * 16 + r;
        tile[kk][tc] = src[(size_t)(k0 + kk) * 1024 + n0 + tc];
    }
    __syncthreads();
    #pragma unroll
    for (int r = 0; r < 16; ++r) {
        const int nl = tq * 16 + r;
        const int n = n0 + nl;
        const int k = k0 + tc;
        const unsigned short v = f2bf(tile[tc][nl]);
        if (z < 4) {
            Whp[(size_t)(((n >> 4) << 6) + (z << 4) + (n & 15)) * 1024 + k] = v;
        } else if (z < 8) {
            Wip[(size_t)(((n >> 4) << 6) + ((z - 4) << 4) + (n & 15)) * 1024 + k] = v;
        } else {
            Wy[(size_t)n * 1024 + k] = v;
        }
    }
}

// ---------------------------------------------------------------------------
__global__ __launch_bounds__(256) void convert_x(const float* __restrict__ x,
                                                 unsigned short* __restrict__ xT) {
    const size_t gid = (size_t)blockIdx.x * 256 + threadIdx.x;
    const int i0 = (int)(gid & 255) * 4;
    const size_t row = gid >> 8;            // dst row = t*64 + b
    const int t = (int)(row >> 6), b = (int)(row & 63);
    const float4 v = *reinterpret_cast<const float4*>(x + (((size_t)b * 512 + t) << 10) + i0);
    ushort4 o;
    o.x = f2bf(v.x); o.y = f2bf(v.y); o.z = f2bf(v.z); o.w = f2bf(v.w);
    *reinterpret_cast<ushort4*>(xT + (row << 10) + i0) = o;
}

// ---------------------------------------------------------------------------
// Persistent sequential LSTM. grid=64 (one block per 16 hidden units),
// 512 threads = 8 waves. Waves 0-3: h @ W_h (K-slices of 1024);
// waves 4-7: x_t @ W_i. One grid barrier per step.
// ---------------------------------------------------------------------------
__global__ __launch_bounds__(512, 2) void lstm_seq(const unsigned short* __restrict__ xT,
                                                   const unsigned short* __restrict__ Whp,
                                                   const unsigned short* __restrict__ Wip,
                                                   unsigned short* __restrict__ h0,
                                                   unsigned short* __restrict__ h1,
                                                   int* __restrict__ bar) {
    const int tid = threadIdx.x;
    const int w = tid >> 6;           // 0..7
    const int lane = tid & 63;
    const int lr = lane & 15;
    const int kq = lane >> 4;
    const int blk = blockIdx.x;
    const int k0 = (w & 3) * 256;
    const bool isX = (w >= 4);

    const unsigned short* __restrict__ Bb = (isX ? Wip : Whp) + (size_t)blk * (64 * 1024);

    __shared__ float red[4][64][64];   // 64 KB
    float creg0 = 0.f, creg1 = 0.f;    // c state: items tid and tid+512

    for (int t = 0; t < 512; ++t) {
        const unsigned short* __restrict__ hin  = (t & 1) ? h1 : h0;
        unsigned short* __restrict__       hout = (t & 1) ? h0 : h1;
        const unsigned short* __restrict__ Ab = isX ? (xT + ((size_t)t << 16)) : hin;

        f32x4 acc[4][4] = {};
        #pragma unroll 2
        for (int it = 0; it < 8; ++it) {
            const int k = k0 + it * 32 + kq * 8;
            bfv8 a[4], b[4];
            #pragma unroll
            for (int m = 0; m < 4; ++m)
                a[m] = *reinterpret_cast<const bfv8*>(Ab + (size_t)(m * 16 + lr) * 1024 + k);
            #pragma unroll
            for (int n = 0; n < 4; ++n)
                b[n] = *reinterpret_cast<const bfv8*>(Bb + (size_t)(n * 16 + lr) * 1024 + k);
            #pragma unroll
            for (int m = 0; m < 4; ++m)
                #pragma unroll
                for (int n = 0; n < 4; ++n)
                    acc[m][n] = __builtin_amdgcn_mfma_f32_16x16x32_bf16(a[m], b[n], acc[m][n], 0, 0, 0);
        }

        // two-stage cross-wave reduce: x-waves store, h-waves accumulate
        if (isX) {
            #pragma unroll
            for (int m = 0; m < 4; ++m)
                #pragma unroll
                for (int n = 0; n < 4; ++n)
                    #pragma unroll
                    for (int r = 0; r < 4; ++r)
                        red[w - 4][m * 16 + kq * 4 + r][n * 16 + lr] = acc[m][n][r];
        }
        __syncthreads();
        if (!isX) {
            #pragma unroll
            for (int m = 0; m < 4; ++m)
                #pragma unroll
                for (int n = 0; n < 4; ++n)
                    #pragma unroll
                    for (int r = 0; r < 4; ++r)
                        red[w][m * 16 + kq * 4 + r][n * 16 + lr] += acc[m][n][r];
        }
        __syncthreads();

        // gate epilogue: 1024 items, 2 per thread; c lives in registers
        #pragma unroll
        for (int u = 0; u < 2; ++u) {
            const int item = u * 512 + tid;
            const int b = item >> 4;
            const int jr = item & 15;
            float pi = 0.f, pf = 0.f, po = 0.f, pg = 0.f;
            #pragma unroll
            for (int ww = 0; ww < 4; ++ww) {
                pi += red[ww][b][jr];
                pf += red[ww][b][16 + jr];
                po += red[ww][b][32 + jr];
                pg += red[ww][b][48 + jr];
            }
            const float co = u ? creg1 : creg0;
            const float ig = 1.f / (1.f + __expf(-pi));
            const float fg = 1.f / (1.f + __expf(-pf));
            const float og = 1.f / (1.f + __expf(-po));
            const float gg = 1.f - 2.f / (__expf(2.f * pg) + 1.f);
            const float cn = fg * co + ig * gg;
            const float hn = og * (1.f - 2.f / (__expf(2.f * cn) + 1.f));
            if (u) creg1 = cn; else creg0 = cn;
            hout[b * 1024 + blk * 16 + jr] = f2bf(hn);
        }

        // ---- grid barrier (monotonic counter, device scope) ----
        __syncthreads();   // drains this block's vmem stores (vmcnt(0) before s_barrier)
        if (tid == 0) {
            __hip_atomic_fetch_add(bar, 1, __ATOMIC_RELEASE, __HIP_MEMORY_SCOPE_AGENT);
            const int target = (t + 1) * 64;
            while (__hip_atomic_load(bar, __ATOMIC_RELAXED, __HIP_MEMORY_SCOPE_AGENT) < target) { }
            __threadfence();  // acquire: invalidate L1/L2 so fresh h is visible
        }
        __syncthreads();
    }
}

// ---------------------------------------------------------------------------
__global__ __launch_bounds__(256) void final_gemm(const unsigned short* __restrict__ h_in,
                                                  const unsigned short* __restrict__ WyT,
                                                  float* __restrict__ out) {
    const int tid = threadIdx.x;
    const int w = tid >> 6;
    const int lane = tid & 63;
    const int lr = lane & 15;
    const int kq = lane >> 4;
    const int c0 = blockIdx.x * 16;
    const int k0 = w * 256;

    f32x4 acc[4] = {};
    #pragma unroll 2
    for (int it = 0; it < 8; ++it) {
        const int k = k0 + it * 32 + kq * 8;
        const bfv8 bfr = *reinterpret_cast<const bfv8*>(WyT + (size_t)(c0 + lr) * 1024 + k);
        #pragma unroll
        for (int m = 0; m < 4; ++m) {
            const bfv8 a = *reinterpret_cast<const bfv8*>(h_in + (size_t)(m * 16 + lr) * 1024 + k);
            acc[m] = __builtin_amdgcn_mfma_f32_16x16x32_bf16(a, bfr, acc[m], 0, 0, 0);
        }
    }
    __shared__ float red[4][64][16];
    #pragma unroll
    for (int m = 0; m < 4; ++m)
        #pragma unroll
        for (int r = 0; r < 4; ++r)
            red[w][m * 16 + kq * 4 + r][lr] = acc[m][r];
    __syncthreads();
    #pragma unroll
    for (int u = 0; u < 4; ++u) {
        const int item = u * 256 + tid;
        const int b = item >> 4;
        const int jr = item & 15;
        const float s = red[0][b][jr] + red[1][b][jr] + red[2][b][jr] + red[3][b][jr];
        out[b * 1024 + c0 + jr] = s;
    }
}

// ---------------------------------------------------------------------------
extern "C" void kernel_launch(void* const* d_in, const int* in_sizes, int n_in,
                              void* d_out, int out_size, void* d_ws, size_t ws_size,
                              hipStream_t stream) {
    const float* x = (const float*)d_in[0];
    SrcPtrs sp;
    sp.p[0] = (const float*)d_in[1]; // W_hi
    sp.p[1] = (const float*)d_in[3]; // W_hf
    sp.p[2] = (const float*)d_in[5]; // W_ho
    sp.p[3] = (const float*)d_in[7]; // W_hg
    sp.p[4] = (const float*)d_in[2]; // W_ii
    sp.p[5] = (const float*)d_in[4]; // W_if
    sp.p[6] = (const float*)d_in[6]; // W_io
    sp.p[7] = (const float*)d_in[8]; // W_ig
    sp.p[8] = (const float*)d_in[9]; // W_y

    char* ws = (char*)d_ws;
    unsigned short* Whp = (unsigned short*)(ws + 0);          //  8 MB
    unsigned short* Wip = (unsigned short*)(ws + 8388608);    //  8 MB
    unsigned short* Wy  = (unsigned short*)(ws + 16777216);   //  2 MB
    unsigned short* xT  = (unsigned short*)(ws + 18874368);   // 64 MB
    unsigned short* h0  = (unsigned short*)(ws + 86245376);   // 128 KB
    unsigned short* h1  = (unsigned short*)(ws + 86376448);   // 128 KB
    int*            bar = (int*)(ws + 86507520);              // 4 B

    pack_weights<<<dim3(16, 16, 9), 256, 0, stream>>>(sp, Whp, Wip, Wy);
    convert_x<<<32768, 256, 0, stream>>>(x, xT);
    hipMemsetAsync(h0, 0, 64 * 1024 * 2, stream);
    hipMemsetAsync(bar, 0, 4, stream);

    lstm_seq<<<64, 512, 0, stream>>>(xT, Whp, Wip, h0, h1, bar);

    final_gemm<<<64, 256, 0, stream>>>(h0, Wy, (float*)d_out);
}

// Round 3
// 6339.017 us; speedup vs baseline: 1.7068x; 1.7068x over previous
//
#include <hip/hip_runtime.h>

// LSTM: B=64, S=512, I=H=O=1024.  bf16 MFMA, fp32 accum.
// Persistent kernel, 64 blocks x 512 thr. Per-wave weight panel resident in
// 128 VGPRs for all 512 steps. h exchanged via device-coherent (sc0 sc1)
// loads/stores; grid barrier is a fence-free relaxed monotonic counter, so
// L2 is NEVER invalidated and weights/xT stay cached.

typedef __bf16 bfv8 __attribute__((ext_vector_type(8)));
typedef float f32x4 __attribute__((ext_vector_type(4)));

__device__ __forceinline__ unsigned short f2bf(float x) {
    union { float f; unsigned int u; } v; v.f = x;
    unsigned int r = (v.u + 0x7FFFu + ((v.u >> 16) & 1u)) >> 16;
    return (unsigned short)r;
}

struct SrcPtrs { const float* p[9]; };

// Coherent (device-scope) 8-load batch: 2 k-steps x 4 row-tiles, 16B each.
// s_waitcnt inside the asm block => outputs valid when block completes (safe).
#define HB(A, P0, P1, P2, P3, O0, O1)                                        \
    asm volatile(                                                            \
        "global_load_dwordx4 %0, %8, off offset:" O0 " sc0 sc1\n\t"         \
        "global_load_dwordx4 %1, %9, off offset:" O0 " sc0 sc1\n\t"         \
        "global_load_dwordx4 %2, %10, off offset:" O0 " sc0 sc1\n\t"        \
        "global_load_dwordx4 %3, %11, off offset:" O0 " sc0 sc1\n\t"        \
        "global_load_dwordx4 %4, %8, off offset:" O1 " sc0 sc1\n\t"         \
        "global_load_dwordx4 %5, %9, off offset:" O1 " sc0 sc1\n\t"         \
        "global_load_dwordx4 %6, %10, off offset:" O1 " sc0 sc1\n\t"        \
        "global_load_dwordx4 %7, %11, off offset:" O1 " sc0 sc1\n\t"        \
        "s_waitcnt vmcnt(0)"                                                 \
        : "=v"(A[0]), "=v"(A[1]), "=v"(A[2]), "=v"(A[3]),                    \
          "=v"(A[4]), "=v"(A[5]), "=v"(A[6]), "=v"(A[7])                     \
        : "v"(P0), "v"(P1), "v"(P2), "v"(P3)                                 \
        : "memory")

// ---------------------------------------------------------------------------
__global__ __launch_bounds__(256) void pack_weights(SrcPtrs sp,
                                                    unsigned short* __restrict__ Whp,
                                                    unsigned short* __restrict__ Wip,
                                                    unsigned short* __restrict__ Wy) {
    __shared__ float tile[64][65];
    const int z = blockIdx.z;
    const float* __restrict__ src = sp.p[z];
    const int n0 = blockIdx.x * 64, k0 = blockIdx.y * 64;
    const int tc = threadIdx.x & 63, tq = threadIdx.x >> 6;

    #pragma unroll
    for (int r = 0; r < 16; ++r) {
        const int kk = tq * 16 + r;
        tile[kk][tc] = src[(size_t)(k0 + kk) * 1024 + n0 + tc];
    }
    __syncthreads();
    #pragma unroll
    for (int r = 0; r < 16; ++r) {
        const int nl = tq * 16 + r;
        const int n = n0 + nl;
        const int k = k0 + tc;
        const unsigned short v = f2bf(tile[tc][nl]);
        if (z < 4) {
            Whp[(size_t)(((n >> 4) << 6) + (z << 4) + (n & 15)) * 1024 + k] = v;
        } else if (z < 8) {
            Wip[(size_t)(((n >> 4) << 6) + ((z - 4) << 4) + (n & 15)) * 1024 + k] = v;
        } else {
            Wy[(size_t)n * 1024 + k] = v;
        }
    }
}

// ---------------------------------------------------------------------------
__global__ __launch_bounds__(256) void convert_x(const float* __restrict__ x,
                                                 unsigned short* __restrict__ xT) {
    const size_t gid = (size_t)blockIdx.x * 256 + threadIdx.x;
    const int i0 = (int)(gid & 255) * 4;
    const size_t row = gid >> 8;            // dst row = t*64 + b
    const int t = (int)(row >> 6), b = (int)(row & 63);
    const float4 v = *reinterpret_cast<const float4*>(x + (((size_t)b * 512 + t) << 10) + i0);
    ushort4 o;
    o.x = f2bf(v.x); o.y = f2bf(v.y); o.z = f2bf(v.z); o.w = f2bf(v.w);
    *reinterpret_cast<ushort4*>(xT + (row << 10) + i0) = o;
}

// ---------------------------------------------------------------------------
// Persistent sequential LSTM. grid=64 (16 hidden units each), 512 thr = 8 waves.
// Waves 0-3: h @ W_h (K slices of 256); waves 4-7: x_t @ W_i.
// ---------------------------------------------------------------------------
__global__ __launch_bounds__(512, 2) void lstm_seq(const unsigned short* __restrict__ xT,
                                                   const unsigned short* __restrict__ Whp,
                                                   const unsigned short* __restrict__ Wip,
                                                   unsigned short* __restrict__ h0,
                                                   unsigned short* __restrict__ h1,
                                                   int* __restrict__ bar) {
    const int tid = threadIdx.x;
    const int w = tid >> 6;           // 0..7
    const int lane = tid & 63;
    const int lr = lane & 15;
    const int kq = lane >> 4;
    const int blk = blockIdx.x;
    const int k0 = (w & 3) * 256;
    const bool isX = (w >= 4);

    // ---- weight panel resident in registers: 32 x bfv8 = 128 VGPR ----
    bfv8 breg[32];
    {
        const unsigned short* __restrict__ Bb = (isX ? Wip : Whp) + ((size_t)blk << 16);
        #pragma unroll
        for (int it = 0; it < 8; ++it)
            #pragma unroll
            for (int n = 0; n < 4; ++n)
                breg[it * 4 + n] = *reinterpret_cast<const bfv8*>(
                    Bb + (size_t)(n * 16 + lr) * 1024 + k0 + it * 32 + kq * 8);
    }

    __shared__ float red[4][64][65];   // padded: no bank conflicts

    float ca = 0.f, cb = 0.f;          // cell state, 2 values per thread
    const int be = tid >> 3;           // epilogue row 0..63
    const int pr = tid & 7;            // epilogue col-pair 0..7

    for (int t = 0; t < 512; ++t) {
        const unsigned short* __restrict__ hin  = (t & 1) ? h1 : h0;
        unsigned short* __restrict__       hout = (t & 1) ? h0 : h1;

        f32x4 acc[4][4] = {};

        if (isX) {
            const unsigned short* __restrict__ Ax =
                xT + ((size_t)t << 16) + (size_t)lr * 1024 + k0 + kq * 8;
            #pragma unroll
            for (int it = 0; it < 8; ++it) {
                bfv8 a[4];
                #pragma unroll
                for (int m = 0; m < 4; ++m)
                    a[m] = *reinterpret_cast<const bfv8*>(Ax + (size_t)m * 16384 + it * 32);
                #pragma unroll
                for (int m = 0; m < 4; ++m)
                    #pragma unroll
                    for (int n = 0; n < 4; ++n)
                        acc[m][n] = __builtin_amdgcn_mfma_f32_16x16x32_bf16(a[m], breg[it * 4 + n], acc[m][n], 0, 0, 0);
            }
            // stage 1: x-waves deposit partials
            #pragma unroll
            for (int m = 0; m < 4; ++m)
                #pragma unroll
                for (int n = 0; n < 4; ++n)
                    #pragma unroll
                    for (int r = 0; r < 4; ++r)
                        red[w - 4][m * 16 + kq * 4 + r][n * 16 + lr] = acc[m][n][r];
        } else {
            // coherent h loads (bypass stale L1/L2; fresh from LLC)
            const unsigned short* hp0 = hin + (size_t)lr * 1024 + k0 + kq * 8;
            const unsigned short* hp1 = hp0 + 16 * 1024;
            const unsigned short* hp2 = hp0 + 32 * 1024;
            const unsigned short* hp3 = hp0 + 48 * 1024;
            #pragma unroll
            for (int bi = 0; bi < 4; ++bi) {
                bfv8 a[8];
                switch (bi) {
                    case 0: HB(a, hp0, hp1, hp2, hp3, "0",   "64");  break;
                    case 1: HB(a, hp0, hp1, hp2, hp3, "128", "192"); break;
                    case 2: HB(a, hp0, hp1, hp2, hp3, "256", "320"); break;
                    default: HB(a, hp0, hp1, hp2, hp3, "384", "448"); break;
                }
                #pragma unroll
                for (int m = 0; m < 4; ++m)
                    #pragma unroll
                    for (int n = 0; n < 4; ++n)
                        acc[m][n] = __builtin_amdgcn_mfma_f32_16x16x32_bf16(a[m], breg[(2 * bi) * 4 + n], acc[m][n], 0, 0, 0);
                #pragma unroll
                for (int m = 0; m < 4; ++m)
                    #pragma unroll
                    for (int n = 0; n < 4; ++n)
                        acc[m][n] = __builtin_amdgcn_mfma_f32_16x16x32_bf16(a[4 + m], breg[(2 * bi + 1) * 4 + n], acc[m][n], 0, 0, 0);
            }
        }

        __syncthreads();
        // stage 2: h-waves accumulate on top of x partials
        if (!isX) {
            #pragma unroll
            for (int m = 0; m < 4; ++m)
                #pragma unroll
                for (int n = 0; n < 4; ++n)
                    #pragma unroll
                    for (int r = 0; r < 4; ++r)
                        red[w][m * 16 + kq * 4 + r][n * 16 + lr] += acc[m][n][r];
        }
        __syncthreads();

        // gate epilogue: one (b, j-pair) per thread; c in registers
        {
            const int j0 = pr << 1;
            float pi0 = 0.f, pf0 = 0.f, po0 = 0.f, pg0 = 0.f;
            float pi1 = 0.f, pf1 = 0.f, po1 = 0.f, pg1 = 0.f;
            #pragma unroll
            for (int ww = 0; ww < 4; ++ww) {
                pi0 += red[ww][be][j0];      pi1 += red[ww][be][j0 + 1];
                pf0 += red[ww][be][16 + j0]; pf1 += red[ww][be][16 + j0 + 1];
                po0 += red[ww][be][32 + j0]; po1 += red[ww][be][32 + j0 + 1];
                pg0 += red[ww][be][48 + j0]; pg1 += red[ww][be][48 + j0 + 1];
            }
            const float ig0 = 1.f / (1.f + __expf(-pi0));
            const float fg0 = 1.f / (1.f + __expf(-pf0));
            const float og0 = 1.f / (1.f + __expf(-po0));
            const float gg0 = 1.f - 2.f / (__expf(2.f * pg0) + 1.f);
            const float cn0 = fg0 * ca + ig0 * gg0;
            const float hn0 = og0 * (1.f - 2.f / (__expf(2.f * cn0) + 1.f));
            ca = cn0;
            const float ig1 = 1.f / (1.f + __expf(-pi1));
            const float fg1 = 1.f / (1.f + __expf(-pf1));
            const float og1 = 1.f / (1.f + __expf(-po1));
            const float gg1 = 1.f - 2.f / (__expf(2.f * pg1) + 1.f);
            const float cn1 = fg1 * cb + ig1 * gg1;
            const float hn1 = og1 * (1.f - 2.f / (__expf(2.f * cn1) + 1.f));
            cb = cn1;
            const unsigned hv = (unsigned)f2bf(hn0) | ((unsigned)f2bf(hn1) << 16);
            // device-coherent store: at LLC once retired (before barrier add)
            __hip_atomic_store(((unsigned*)hout) + ((be << 9) + (blk << 3) + pr), hv,
                               __ATOMIC_RELAXED, __HIP_MEMORY_SCOPE_AGENT);
        }

        // ---- fence-free grid barrier (relaxed monotonic counter) ----
        asm volatile("s_waitcnt vmcnt(0)" ::: "memory");
        __syncthreads();   // all waves' h stores retired before tid0 proceeds
        if (tid == 0) {
            __hip_atomic_fetch_add(bar, 1, __ATOMIC_RELAXED, __HIP_MEMORY_SCOPE_AGENT);
            const int target = (t + 1) << 6;
            while (__hip_atomic_load(bar, __ATOMIC_RELAXED, __HIP_MEMORY_SCOPE_AGENT) < target)
                __builtin_amdgcn_s_sleep(1);
        }
        __syncthreads();
    }
}

// ---------------------------------------------------------------------------
__global__ __launch_bounds__(256) void final_gemm(const unsigned short* __restrict__ h_in,
                                                  const unsigned short* __restrict__ WyT,
                                                  float* __restrict__ out) {
    const int tid = threadIdx.x;
    const int w = tid >> 6;
    const int lane = tid & 63;
    const int lr = lane & 15;
    const int kq = lane >> 4;
    const int c0 = blockIdx.x * 16;
    const int k0 = w * 256;

    f32x4 acc[4] = {};
    #pragma unroll 2
    for (int it = 0; it < 8; ++it) {
        const int k = k0 + it * 32 + kq * 8;
        const bfv8 bfr = *reinterpret_cast<const bfv8*>(WyT + (size_t)(c0 + lr) * 1024 + k);
        #pragma unroll
        for (int m = 0; m < 4; ++m) {
            const bfv8 a = *reinterpret_cast<const bfv8*>(h_in + (size_t)(m * 16 + lr) * 1024 + k);
            acc[m] = __builtin_amdgcn_mfma_f32_16x16x32_bf16(a, bfr, acc[m], 0, 0, 0);
        }
    }
    __shared__ float red[4][64][17];
    #pragma unroll
    for (int m = 0; m < 4; ++m)
        #pragma unroll
        for (int r = 0; r < 4; ++r)
            red[w][m * 16 + kq * 4 + r][lr] = acc[m][r];
    __syncthreads();
    #pragma unroll
    for (int u = 0; u < 4; ++u) {
        const int item = u * 256 + tid;
        const int b = item >> 4;
        const int jr = item & 15;
        const float s = red[0][b][jr] + red[1][b][jr] + red[2][b][jr] + red[3][b][jr];
        out[b * 1024 + c0 + jr] = s;
    }
}

// ---------------------------------------------------------------------------
extern "C" void kernel_launch(void* const* d_in, const int* in_sizes, int n_in,
                              void* d_out, int out_size, void* d_ws, size_t ws_size,
                              hipStream_t stream) {
    const float* x = (const float*)d_in[0];
    SrcPtrs sp;
    sp.p[0] = (const float*)d_in[1]; // W_hi
    sp.p[1] = (const float*)d_in[3]; // W_hf
    sp.p[2] = (const float*)d_in[5]; // W_ho
    sp.p[3] = (const float*)d_in[7]; // W_hg
    sp.p[4] = (const float*)d_in[2]; // W_ii
    sp.p[5] = (const float*)d_in[4]; // W_if
    sp.p[6] = (const float*)d_in[6]; // W_io
    sp.p[7] = (const float*)d_in[8]; // W_ig
    sp.p[8] = (const float*)d_in[9]; // W_y

    char* ws = (char*)d_ws;
    unsigned short* Whp = (unsigned short*)(ws + 0);          //  8 MB
    unsigned short* Wip = (unsigned short*)(ws + 8388608);    //  8 MB
    unsigned short* Wy  = (unsigned short*)(ws + 16777216);   //  2 MB
    unsigned short* xT  = (unsigned short*)(ws + 18874368);   // 64 MB
    unsigned short* h0  = (unsigned short*)(ws + 86245376);   // 128 KB
    unsigned short* h1  = (unsigned short*)(ws + 86376448);   // 128 KB
    int*            bar = (int*)(ws + 86507520);              // 4 B

    pack_weights<<<dim3(16, 16, 9), 256, 0, stream>>>(sp, Whp, Wip, Wy);
    convert_x<<<32768, 256, 0, stream>>>(x, xT);
    hipMemsetAsync(h0, 0, 64 * 1024 * 2, stream);
    hipMemsetAsync(bar, 0, 4, stream);

    lstm_seq<<<64, 512, 0, stream>>>(xT, Whp, Wip, h0, h1, bar);

    final_gemm<<<64, 256, 0, stream>>>(h0, Wy, (float*)d_out);
}

// Round 4
// 6338.324 us; speedup vs baseline: 1.7070x; 1.0001x over previous
//
#include <hip/hip_runtime.h>

// LSTM: B=64, S=512, I=H=O=1024.  bf16 MFMA, fp32 accum.
// Persistent kernel, 64 blocks x 512 thr. Per-wave weight panel resident in
// 128 VGPRs for all 512 steps (launch_bounds(512) -> 256-VGPR cap, no spill).
// h exchanged via device-coherent (sc0 sc1) loads/stores; grid barrier is a
// fence-free relaxed monotonic counter, so L2 stays valid and weights/xT
// stay cached.

typedef __bf16 bfv8 __attribute__((ext_vector_type(8)));
typedef float f32x4 __attribute__((ext_vector_type(4)));

__device__ __forceinline__ unsigned short f2bf(float x) {
    union { float f; unsigned int u; } v; v.f = x;
    unsigned int r = (v.u + 0x7FFFu + ((v.u >> 16) & 1u)) >> 16;
    return (unsigned short)r;
}

struct SrcPtrs { const float* p[9]; };

// Coherent (device-scope) 8-load batch: 2 k-steps x 4 row-tiles, 16B each.
// "=&v" early-clobber: async dests must not alias later loads' address regs.
#define HB(A, P0, P1, P2, P3, O0, O1)                                        \
    asm volatile(                                                            \
        "global_load_dwordx4 %0, %8, off offset:" O0 " sc0 sc1\n\t"         \
        "global_load_dwordx4 %1, %9, off offset:" O0 " sc0 sc1\n\t"         \
        "global_load_dwordx4 %2, %10, off offset:" O0 " sc0 sc1\n\t"        \
        "global_load_dwordx4 %3, %11, off offset:" O0 " sc0 sc1\n\t"        \
        "global_load_dwordx4 %4, %8, off offset:" O1 " sc0 sc1\n\t"         \
        "global_load_dwordx4 %5, %9, off offset:" O1 " sc0 sc1\n\t"         \
        "global_load_dwordx4 %6, %10, off offset:" O1 " sc0 sc1\n\t"        \
        "global_load_dwordx4 %7, %11, off offset:" O1 " sc0 sc1\n\t"        \
        "s_waitcnt vmcnt(0)"                                                 \
        : "=&v"(A[0]), "=&v"(A[1]), "=&v"(A[2]), "=&v"(A[3]),                \
          "=&v"(A[4]), "=&v"(A[5]), "=&v"(A[6]), "=&v"(A[7])                 \
        : "v"(P0), "v"(P1), "v"(P2), "v"(P3)                                 \
        : "memory")

// ---------------------------------------------------------------------------
__global__ __launch_bounds__(256) void pack_weights(SrcPtrs sp,
                                                    unsigned short* __restrict__ Whp,
                                                    unsigned short* __restrict__ Wip,
                                                    unsigned short* __restrict__ Wy) {
    __shared__ float tile[64][65];
    const int z = blockIdx.z;
    const float* __restrict__ src = sp.p[z];
    const int n0 = blockIdx.x * 64, k0 = blockIdx.y * 64;
    const int tc = threadIdx.x & 63, tq = threadIdx.x >> 6;

    #pragma unroll
    for (int r = 0; r < 16; ++r) {
        const int kk = tq * 16 + r;
        tile[kk][tc] = src[(size_t)(k0 + kk) * 1024 + n0 + tc];
    }
    __syncthreads();
    #pragma unroll
    for (int r = 0; r < 16; ++r) {
        const int nl = tq * 16 + r;
        const int n = n0 + nl;
        const int k = k0 + tc;
        const unsigned short v = f2bf(tile[tc][nl]);
        if (z < 4) {
            Whp[(size_t)(((n >> 4) << 6) + (z << 4) + (n & 15)) * 1024 + k] = v;
        } else if (z < 8) {
            Wip[(size_t)(((n >> 4) << 6) + ((z - 4) << 4) + (n & 15)) * 1024 + k] = v;
        } else {
            Wy[(size_t)n * 1024 + k] = v;
        }
    }
}

// ---------------------------------------------------------------------------
__global__ __launch_bounds__(256) void convert_x(const float* __restrict__ x,
                                                 unsigned short* __restrict__ xT) {
    const size_t gid = (size_t)blockIdx.x * 256 + threadIdx.x;
    const int i0 = (int)(gid & 255) * 4;
    const size_t row = gid >> 8;            // dst row = t*64 + b
    const int t = (int)(row >> 6), b = (int)(row & 63);
    const float4 v = *reinterpret_cast<const float4*>(x + (((size_t)b * 512 + t) << 10) + i0);
    ushort4 o;
    o.x = f2bf(v.x); o.y = f2bf(v.y); o.z = f2bf(v.z); o.w = f2bf(v.w);
    *reinterpret_cast<ushort4*>(xT + (row << 10) + i0) = o;
}

// ---------------------------------------------------------------------------
// Persistent sequential LSTM. grid=64 (16 hidden units each), 512 thr = 8 waves.
// Waves 0-3: h @ W_h (K slices of 256); waves 4-7: x_t @ W_i.
// ---------------------------------------------------------------------------
__global__ __launch_bounds__(512) void lstm_seq(const unsigned short* __restrict__ xT,
                                                const unsigned short* __restrict__ Whp,
                                                const unsigned short* __restrict__ Wip,
                                                unsigned short* __restrict__ h0,
                                                unsigned short* __restrict__ h1,
                                                int* __restrict__ bar) {
    const int tid = threadIdx.x;
    const int w = tid >> 6;           // 0..7
    const int lane = tid & 63;
    const int lr = lane & 15;
    const int kq = lane >> 4;
    const int blk = blockIdx.x;
    const int k0 = (w & 3) * 256;
    const bool isX = (w >= 4);

    // ---- weight panel resident in registers: 32 x bfv8 = 128 VGPR ----
    bfv8 breg[32];
    {
        const unsigned short* __restrict__ Bb = (isX ? Wip : Whp) + ((size_t)blk << 16);
        #pragma unroll
        for (int it = 0; it < 8; ++it)
            #pragma unroll
            for (int n = 0; n < 4; ++n)
                breg[it * 4 + n] = *reinterpret_cast<const bfv8*>(
                    Bb + (size_t)(n * 16 + lr) * 1024 + k0 + it * 32 + kq * 8);
    }

    __shared__ float red[4][64][65];   // padded

    float ca = 0.f, cb = 0.f;          // cell state, 2 values per thread
    const int be = tid >> 3;           // epilogue row 0..63
    const int pr = tid & 7;            // epilogue col-pair 0..7

    for (int t = 0; t < 512; ++t) {
        const unsigned short* __restrict__ hin  = (t & 1) ? h1 : h0;
        unsigned short* __restrict__       hout = (t & 1) ? h0 : h1;

        f32x4 acc[4][4] = {};

        if (isX) {
            const unsigned short* __restrict__ Ax =
                xT + ((size_t)t << 16) + (size_t)lr * 1024 + k0 + kq * 8;
            #pragma unroll
            for (int it = 0; it < 8; ++it) {
                bfv8 a[4];
                #pragma unroll
                for (int m = 0; m < 4; ++m)
                    a[m] = *reinterpret_cast<const bfv8*>(Ax + (size_t)m * 16384 + it * 32);
                #pragma unroll
                for (int m = 0; m < 4; ++m)
                    #pragma unroll
                    for (int n = 0; n < 4; ++n)
                        acc[m][n] = __builtin_amdgcn_mfma_f32_16x16x32_bf16(a[m], breg[it * 4 + n], acc[m][n], 0, 0, 0);
            }
            // stage 1: x-waves deposit partials
            #pragma unroll
            for (int m = 0; m < 4; ++m)
                #pragma unroll
                for (int n = 0; n < 4; ++n)
                    #pragma unroll
                    for (int r = 0; r < 4; ++r)
                        red[w - 4][m * 16 + kq * 4 + r][n * 16 + lr] = acc[m][n][r];
        } else {
            // coherent h loads (bypass stale L1/L2; fresh from LLC)
            const unsigned short* hp0 = hin + (size_t)lr * 1024 + k0 + kq * 8;
            const unsigned short* hp1 = hp0 + 16 * 1024;
            const unsigned short* hp2 = hp0 + 32 * 1024;
            const unsigned short* hp3 = hp0 + 48 * 1024;
            #pragma unroll
            for (int bi = 0; bi < 4; ++bi) {
                bfv8 a[8];
                switch (bi) {
                    case 0: HB(a, hp0, hp1, hp2, hp3, "0",   "64");  break;
                    case 1: HB(a, hp0, hp1, hp2, hp3, "128", "192"); break;
                    case 2: HB(a, hp0, hp1, hp2, hp3, "256", "320"); break;
                    default: HB(a, hp0, hp1, hp2, hp3, "384", "448"); break;
                }
                #pragma unroll
                for (int m = 0; m < 4; ++m)
                    #pragma unroll
                    for (int n = 0; n < 4; ++n)
                        acc[m][n] = __builtin_amdgcn_mfma_f32_16x16x32_bf16(a[m], breg[(2 * bi) * 4 + n], acc[m][n], 0, 0, 0);
                #pragma unroll
                for (int m = 0; m < 4; ++m)
                    #pragma unroll
                    for (int n = 0; n < 4; ++n)
                        acc[m][n] = __builtin_amdgcn_mfma_f32_16x16x32_bf16(a[4 + m], breg[(2 * bi + 1) * 4 + n], acc[m][n], 0, 0, 0);
            }
        }

        __syncthreads();
        // stage 2: h-waves accumulate on top of x partials
        if (!isX) {
            #pragma unroll
            for (int m = 0; m < 4; ++m)
                #pragma unroll
                for (int n = 0; n < 4; ++n)
                    #pragma unroll
                    for (int r = 0; r < 4; ++r)
                        red[w][m * 16 + kq * 4 + r][n * 16 + lr] += acc[m][n][r];
        }
        __syncthreads();

        // gate epilogue: one (b, j-pair) per thread; c in registers
        {
            const int j0 = pr << 1;
            float pi0 = 0.f, pf0 = 0.f, po0 = 0.f, pg0 = 0.f;
            float pi1 = 0.f, pf1 = 0.f, po1 = 0.f, pg1 = 0.f;
            #pragma unroll
            for (int ww = 0; ww < 4; ++ww) {
                pi0 += red[ww][be][j0];      pi1 += red[ww][be][j0 + 1];
                pf0 += red[ww][be][16 + j0]; pf1 += red[ww][be][16 + j0 + 1];
                po0 += red[ww][be][32 + j0]; po1 += red[ww][be][32 + j0 + 1];
                pg0 += red[ww][be][48 + j0]; pg1 += red[ww][be][48 + j0 + 1];
            }
            const float ig0 = 1.f / (1.f + __expf(-pi0));
            const float fg0 = 1.f / (1.f + __expf(-pf0));
            const float og0 = 1.f / (1.f + __expf(-po0));
            const float gg0 = 1.f - 2.f / (__expf(2.f * pg0) + 1.f);
            const float cn0 = fg0 * ca + ig0 * gg0;
            const float hn0 = og0 * (1.f - 2.f / (__expf(2.f * cn0) + 1.f));
            ca = cn0;
            const float ig1 = 1.f / (1.f + __expf(-pi1));
            const float fg1 = 1.f / (1.f + __expf(-pf1));
            const float og1 = 1.f / (1.f + __expf(-po1));
            const float gg1 = 1.f - 2.f / (__expf(2.f * pg1) + 1.f);
            const float cn1 = fg1 * cb + ig1 * gg1;
            const float hn1 = og1 * (1.f - 2.f / (__expf(2.f * cn1) + 1.f));
            cb = cn1;
            const unsigned hv = (unsigned)f2bf(hn0) | ((unsigned)f2bf(hn1) << 16);
            // device-coherent store: at LLC once retired (before barrier add)
            __hip_atomic_store(((unsigned*)hout) + ((be << 9) + (blk << 3) + pr), hv,
                               __ATOMIC_RELAXED, __HIP_MEMORY_SCOPE_AGENT);
        }

        // ---- fence-free grid barrier (relaxed monotonic counter) ----
        asm volatile("s_waitcnt vmcnt(0)" ::: "memory");
        __syncthreads();   // all waves' h stores retired before tid0 proceeds
        if (tid == 0) {
            __hip_atomic_fetch_add(bar, 1, __ATOMIC_RELAXED, __HIP_MEMORY_SCOPE_AGENT);
            const int target = (t + 1) << 6;
            while (__hip_atomic_load(bar, __ATOMIC_RELAXED, __HIP_MEMORY_SCOPE_AGENT) < target)
                __builtin_amdgcn_s_sleep(1);
        }
        __syncthreads();
    }
}

// ---------------------------------------------------------------------------
__global__ __launch_bounds__(256) void final_gemm(const unsigned short* __restrict__ h_in,
                                                  const unsigned short* __restrict__ WyT,
                                                  float* __restrict__ out) {
    const int tid = threadIdx.x;
    const int w = tid >> 6;
    const int lane = tid & 63;
    const int lr = lane & 15;
    const int kq = lane >> 4;
    const int c0 = blockIdx.x * 16;
    const int k0 = w * 256;

    f32x4 acc[4] = {};
    #pragma unroll 2
    for (int it = 0; it < 8; ++it) {
        const int k = k0 + it * 32 + kq * 8;
        const bfv8 bfr = *reinterpret_cast<const bfv8*>(WyT + (size_t)(c0 + lr) * 1024 + k);
        #pragma unroll
        for (int m = 0; m < 4; ++m) {
            const bfv8 a = *reinterpret_cast<const bfv8*>(h_in + (size_t)(m * 16 + lr) * 1024 + k);
            acc[m] = __builtin_amdgcn_mfma_f32_16x16x32_bf16(a, bfr, acc[m], 0, 0, 0);
        }
    }
    __shared__ float red[4][64][17];
    #pragma unroll
    for (int m = 0; m < 4; ++m)
        #pragma unroll
        for (int r = 0; r < 4; ++r)
            red[w][m * 16 + kq * 4 + r][lr] = acc[m][r];
    __syncthreads();
    #pragma unroll
    for (int u = 0; u < 4; ++u) {
        const int item = u * 256 + tid;
        const int b = item >> 4;
        const int jr = item & 15;
        const float s = red[0][b][jr] + red[1][b][jr] + red[2][b][jr] + red[3][b][jr];
        out[b * 1024 + c0 + jr] = s;
    }
}

// ---------------------------------------------------------------------------
extern "C" void kernel_launch(void* const* d_in, const int* in_sizes, int n_in,
                              void* d_out, int out_size, void* d_ws, size_t ws_size,
                              hipStream_t stream) {
    const float* x = (const float*)d_in[0];
    SrcPtrs sp;
    sp.p[0] = (const float*)d_in[1]; // W_hi
    sp.p[1] = (const float*)d_in[3]; // W_hf
    sp.p[2] = (const float*)d_in[5]; // W_ho
    sp.p[3] = (const float*)d_in[7]; // W_hg
    sp.p[4] = (const float*)d_in[2]; // W_ii
    sp.p[5] = (const float*)d_in[4]; // W_if
    sp.p[6] = (const float*)d_in[6]; // W_io
    sp.p[7] = (const float*)d_in[8]; // W_ig
    sp.p[8] = (const float*)d_in[9]; // W_y

    char* ws = (char*)d_ws;
    unsigned short* Whp = (unsigned short*)(ws + 0);          //  8 MB
    unsigned short* Wip = (unsigned short*)(ws + 8388608);    //  8 MB
    unsigned short* Wy  = (unsigned short*)(ws + 16777216);   //  2 MB
    unsigned short* xT  = (unsigned short*)(ws + 18874368);   // 64 MB
    unsigned short* h0  = (unsigned short*)(ws + 86245376);   // 128 KB
    unsigned short* h1  = (unsigned short*)(ws + 86376448);   // 128 KB
    int*            bar = (int*)(ws + 86507520);              // 4 B

    pack_weights<<<dim3(16, 16, 9), 256, 0, stream>>>(sp, Whp, Wip, Wy);
    convert_x<<<32768, 256, 0, stream>>>(x, xT);
    hipMemsetAsync(h0, 0, 64 * 1024 * 2, stream);
    hipMemsetAsync(bar, 0, 4, stream);

    lstm_seq<<<64, 512, 0, stream>>>(xT, Whp, Wip, h0, h1, bar);

    final_gemm<<<64, 256, 0, stream>>>(h0, Wy, (float*)d_out);
}

// Round 5
// 6337.698 us; speedup vs baseline: 1.7071x; 1.0001x over previous
//
#include <hip/hip_runtime.h>

// LSTM: B=64, S=512, I=H=O=1024.  bf16 MFMA, fp32 accum.
// Persistent kernel, 64 blocks x 512 thr. Per-wave weight panel resident in
// 128 VGPRs for all 512 steps. amdgpu_waves_per_eu(2,2) lifts the default
// 4-waves/EU register cap (128) to 256 so breg does NOT spill.
// h exchanged via device-coherent (sc0 sc1) loads/stores; grid barrier is a
// fence-free relaxed monotonic counter, so L2 stays valid and weights/xT
// stay cached.

typedef __bf16 bfv8 __attribute__((ext_vector_type(8)));
typedef float f32x4 __attribute__((ext_vector_type(4)));

__device__ __forceinline__ unsigned short f2bf(float x) {
    union { float f; unsigned int u; } v; v.f = x;
    unsigned int r = (v.u + 0x7FFFu + ((v.u >> 16) & 1u)) >> 16;
    return (unsigned short)r;
}

struct SrcPtrs { const float* p[9]; };

// Coherent (device-scope) 8-load batch: 2 k-steps x 4 row-tiles, 16B each.
// "=&v" early-clobber: async dests must not alias later loads' address regs.
#define HB(A, P0, P1, P2, P3, O0, O1)                                        \
    asm volatile(                                                            \
        "global_load_dwordx4 %0, %8, off offset:" O0 " sc0 sc1\n\t"         \
        "global_load_dwordx4 %1, %9, off offset:" O0 " sc0 sc1\n\t"         \
        "global_load_dwordx4 %2, %10, off offset:" O0 " sc0 sc1\n\t"        \
        "global_load_dwordx4 %3, %11, off offset:" O0 " sc0 sc1\n\t"        \
        "global_load_dwordx4 %4, %8, off offset:" O1 " sc0 sc1\n\t"         \
        "global_load_dwordx4 %5, %9, off offset:" O1 " sc0 sc1\n\t"         \
        "global_load_dwordx4 %6, %10, off offset:" O1 " sc0 sc1\n\t"        \
        "global_load_dwordx4 %7, %11, off offset:" O1 " sc0 sc1\n\t"        \
        "s_waitcnt vmcnt(0)"                                                 \
        : "=&v"(A[0]), "=&v"(A[1]), "=&v"(A[2]), "=&v"(A[3]),                \
          "=&v"(A[4]), "=&v"(A[5]), "=&v"(A[6]), "=&v"(A[7])                 \
        : "v"(P0), "v"(P1), "v"(P2), "v"(P3)                                 \
        : "memory")

// ---------------------------------------------------------------------------
__global__ __launch_bounds__(256) void pack_weights(SrcPtrs sp,
                                                    unsigned short* __restrict__ Whp,
                                                    unsigned short* __restrict__ Wip,
                                                    unsigned short* __restrict__ Wy) {
    __shared__ float tile[64][65];
    const int z = blockIdx.z;
    const float* __restrict__ src = sp.p[z];
    const int n0 = blockIdx.x * 64, k0 = blockIdx.y * 64;
    const int tc = threadIdx.x & 63, tq = threadIdx.x >> 6;

    #pragma unroll
    for (int r = 0; r < 16; ++r) {
        const int kk = tq * 16 + r;
        tile[kk][tc] = src[(size_t)(k0 + kk) * 1024 + n0 + tc];
    }
    __syncthreads();
    #pragma unroll
    for (int r = 0; r < 16; ++r) {
        const int nl = tq * 16 + r;
        const int n = n0 + nl;
        const int k = k0 + tc;
        const unsigned short v = f2bf(tile[tc][nl]);
        if (z < 4) {
            Whp[(size_t)(((n >> 4) << 6) + (z << 4) + (n & 15)) * 1024 + k] = v;
        } else if (z < 8) {
            Wip[(size_t)(((n >> 4) << 6) + ((z - 4) << 4) + (n & 15)) * 1024 + k] = v;
        } else {
            Wy[(size_t)n * 1024 + k] = v;
        }
    }
}

// ---------------------------------------------------------------------------
__global__ __launch_bounds__(256) void convert_x(const float* __restrict__ x,
                                                 unsigned short* __restrict__ xT) {
    const size_t gid = (size_t)blockIdx.x * 256 + threadIdx.x;
    const int i0 = (int)(gid & 255) * 4;
    const size_t row = gid >> 8;            // dst row = t*64 + b
    const int t = (int)(row >> 6), b = (int)(row & 63);
    const float4 v = *reinterpret_cast<const float4*>(x + (((size_t)b * 512 + t) << 10) + i0);
    ushort4 o;
    o.x = f2bf(v.x); o.y = f2bf(v.y); o.z = f2bf(v.z); o.w = f2bf(v.w);
    *reinterpret_cast<ushort4*>(xT + (row << 10) + i0) = o;
}

// ---------------------------------------------------------------------------
// Persistent sequential LSTM. grid=64 (16 hidden units each), 512 thr = 8 waves.
// Waves 0-3: h @ W_h (K slices of 256); waves 4-7: x_t @ W_i.
// ---------------------------------------------------------------------------
__global__ __launch_bounds__(512)
__attribute__((amdgpu_waves_per_eu(2, 2)))
void lstm_seq(const unsigned short* __restrict__ xT,
              const unsigned short* __restrict__ Whp,
              const unsigned short* __restrict__ Wip,
              unsigned short* __restrict__ h0,
              unsigned short* __restrict__ h1,
              int* __restrict__ bar) {
    const int tid = threadIdx.x;
    const int w = tid >> 6;           // 0..7
    const int lane = tid & 63;
    const int lr = lane & 15;
    const int kq = lane >> 4;
    const int blk = blockIdx.x;
    const int k0 = (w & 3) * 256;
    const bool isX = (w >= 4);

    // ---- weight panel resident in registers: 32 x bfv8 = 128 VGPR ----
    bfv8 breg[32];
    {
        const unsigned short* __restrict__ Bb = (isX ? Wip : Whp) + ((size_t)blk << 16);
        #pragma unroll
        for (int it = 0; it < 8; ++it)
            #pragma unroll
            for (int n = 0; n < 4; ++n)
                breg[it * 4 + n] = *reinterpret_cast<const bfv8*>(
                    Bb + (size_t)(n * 16 + lr) * 1024 + k0 + it * 32 + kq * 8);
    }

    __shared__ float red[4][64][65];   // padded

    float ca = 0.f, cb = 0.f;          // cell state, 2 values per thread
    const int be = tid >> 3;           // epilogue row 0..63
    const int pr = tid & 7;            // epilogue col-pair 0..7

    for (int t = 0; t < 512; ++t) {
        const unsigned short* __restrict__ hin  = (t & 1) ? h1 : h0;
        unsigned short* __restrict__       hout = (t & 1) ? h0 : h1;

        f32x4 acc[4][4] = {};

        if (isX) {
            const unsigned short* __restrict__ Ax =
                xT + ((size_t)t << 16) + (size_t)lr * 1024 + k0 + kq * 8;
            #pragma unroll
            for (int it = 0; it < 8; ++it) {
                bfv8 a[4];
                #pragma unroll
                for (int m = 0; m < 4; ++m)
                    a[m] = *reinterpret_cast<const bfv8*>(Ax + (size_t)m * 16384 + it * 32);
                #pragma unroll
                for (int m = 0; m < 4; ++m)
                    #pragma unroll
                    for (int n = 0; n < 4; ++n)
                        acc[m][n] = __builtin_amdgcn_mfma_f32_16x16x32_bf16(a[m], breg[it * 4 + n], acc[m][n], 0, 0, 0);
            }
            // stage 1: x-waves deposit partials
            #pragma unroll
            for (int m = 0; m < 4; ++m)
                #pragma unroll
                for (int n = 0; n < 4; ++n)
                    #pragma unroll
                    for (int r = 0; r < 4; ++r)
                        red[w - 4][m * 16 + kq * 4 + r][n * 16 + lr] = acc[m][n][r];
        } else {
            // coherent h loads (bypass stale L1/L2; fresh from LLC)
            const unsigned short* hp0 = hin + (size_t)lr * 1024 + k0 + kq * 8;
            const unsigned short* hp1 = hp0 + 16 * 1024;
            const unsigned short* hp2 = hp0 + 32 * 1024;
            const unsigned short* hp3 = hp0 + 48 * 1024;
            #pragma unroll
            for (int bi = 0; bi < 4; ++bi) {
                bfv8 a[8];
                switch (bi) {
                    case 0: HB(a, hp0, hp1, hp2, hp3, "0",   "64");  break;
                    case 1: HB(a, hp0, hp1, hp2, hp3, "128", "192"); break;
                    case 2: HB(a, hp0, hp1, hp2, hp3, "256", "320"); break;
                    default: HB(a, hp0, hp1, hp2, hp3, "384", "448"); break;
                }
                #pragma unroll
                for (int m = 0; m < 4; ++m)
                    #pragma unroll
                    for (int n = 0; n < 4; ++n)
                        acc[m][n] = __builtin_amdgcn_mfma_f32_16x16x32_bf16(a[m], breg[(2 * bi) * 4 + n], acc[m][n], 0, 0, 0);
                #pragma unroll
                for (int m = 0; m < 4; ++m)
                    #pragma unroll
                    for (int n = 0; n < 4; ++n)
                        acc[m][n] = __builtin_amdgcn_mfma_f32_16x16x32_bf16(a[4 + m], breg[(2 * bi + 1) * 4 + n], acc[m][n], 0, 0, 0);
            }
        }

        __syncthreads();
        // stage 2: h-waves accumulate on top of x partials
        if (!isX) {
            #pragma unroll
            for (int m = 0; m < 4; ++m)
                #pragma unroll
                for (int n = 0; n < 4; ++n)
                    #pragma unroll
                    for (int r = 0; r < 4; ++r)
                        red[w][m * 16 + kq * 4 + r][n * 16 + lr] += acc[m][n][r];
        }
        __syncthreads();

        // gate epilogue: one (b, j-pair) per thread; c in registers
        {
            const int j0 = pr << 1;
            float pi0 = 0.f, pf0 = 0.f, po0 = 0.f, pg0 = 0.f;
            float pi1 = 0.f, pf1 = 0.f, po1 = 0.f, pg1 = 0.f;
            #pragma unroll
            for (int ww = 0; ww < 4; ++ww) {
                pi0 += red[ww][be][j0];      pi1 += red[ww][be][j0 + 1];
                pf0 += red[ww][be][16 + j0]; pf1 += red[ww][be][16 + j0 + 1];
                po0 += red[ww][be][32 + j0]; po1 += red[ww][be][32 + j0 + 1];
                pg0 += red[ww][be][48 + j0]; pg1 += red[ww][be][48 + j0 + 1];
            }
            const float ig0 = 1.f / (1.f + __expf(-pi0));
            const float fg0 = 1.f / (1.f + __expf(-pf0));
            const float og0 = 1.f / (1.f + __expf(-po0));
            const float gg0 = 1.f - 2.f / (__expf(2.f * pg0) + 1.f);
            const float cn0 = fg0 * ca + ig0 * gg0;
            const float hn0 = og0 * (1.f - 2.f / (__expf(2.f * cn0) + 1.f));
            ca = cn0;
            const float ig1 = 1.f / (1.f + __expf(-pi1));
            const float fg1 = 1.f / (1.f + __expf(-pf1));
            const float og1 = 1.f / (1.f + __expf(-po1));
            const float gg1 = 1.f - 2.f / (__expf(2.f * pg1) + 1.f);
            const float cn1 = fg1 * cb + ig1 * gg1;
            const float hn1 = og1 * (1.f - 2.f / (__expf(2.f * cn1) + 1.f));
            cb = cn1;
            const unsigned hv = (unsigned)f2bf(hn0) | ((unsigned)f2bf(hn1) << 16);
            // device-coherent store: at LLC once retired (before barrier add)
            __hip_atomic_store(((unsigned*)hout) + ((be << 9) + (blk << 3) + pr), hv,
                               __ATOMIC_RELAXED, __HIP_MEMORY_SCOPE_AGENT);
        }

        // ---- fence-free grid barrier (relaxed monotonic counter) ----
        asm volatile("s_waitcnt vmcnt(0)" ::: "memory");
        __syncthreads();   // all waves' h stores retired before tid0 proceeds
        if (tid == 0) {
            __hip_atomic_fetch_add(bar, 1, __ATOMIC_RELAXED, __HIP_MEMORY_SCOPE_AGENT);
            const int target = (t + 1) << 6;
            while (__hip_atomic_load(bar, __ATOMIC_RELAXED, __HIP_MEMORY_SCOPE_AGENT) < target)
                __builtin_amdgcn_s_sleep(1);
        }
        __syncthreads();
    }
}

// ---------------------------------------------------------------------------
__global__ __launch_bounds__(256) void final_gemm(const unsigned short* __restrict__ h_in,
                                                  const unsigned short* __restrict__ WyT,
                                                  float* __restrict__ out) {
    const int tid = threadIdx.x;
    const int w = tid >> 6;
    const int lane = tid & 63;
    const int lr = lane & 15;
    const int kq = lane >> 4;
    const int c0 = blockIdx.x * 16;
    const int k0 = w * 256;

    f32x4 acc[4] = {};
    #pragma unroll 2
    for (int it = 0; it < 8; ++it) {
        const int k = k0 + it * 32 + kq * 8;
        const bfv8 bfr = *reinterpret_cast<const bfv8*>(WyT + (size_t)(c0 + lr) * 1024 + k);
        #pragma unroll
        for (int m = 0; m < 4; ++m) {
            const bfv8 a = *reinterpret_cast<const bfv8*>(h_in + (size_t)(m * 16 + lr) * 1024 + k);
            acc[m] = __builtin_amdgcn_mfma_f32_16x16x32_bf16(a, bfr, acc[m], 0, 0, 0);
        }
    }
    __shared__ float red[4][64][17];
    #pragma unroll
    for (int m = 0; m < 4; ++m)
        #pragma unroll
        for (int r = 0; r < 4; ++r)
            red[w][m * 16 + kq * 4 + r][lr] = acc[m][r];
    __syncthreads();
    #pragma unroll
    for (int u = 0; u < 4; ++u) {
        const int item = u * 256 + tid;
        const int b = item >> 4;
        const int jr = item & 15;
        const float s = red[0][b][jr] + red[1][b][jr] + red[2][b][jr] + red[3][b][jr];
        out[b * 1024 + c0 + jr] = s;
    }
}

// ---------------------------------------------------------------------------
extern "C" void kernel_launch(void* const* d_in, const int* in_sizes, int n_in,
                              void* d_out, int out_size, void* d_ws, size_t ws_size,
                              hipStream_t stream) {
    const float* x = (const float*)d_in[0];
    SrcPtrs sp;
    sp.p[0] = (const float*)d_in[1]; // W_hi
    sp.p[1] = (const float*)d_in[3]; // W_hf
    sp.p[2] = (const float*)d_in[5]; // W_ho
    sp.p[3] = (const float*)d_in[7]; // W_hg
    sp.p[4] = (const float*)d_in[2]; // W_ii
    sp.p[5] = (const float*)d_in[4]; // W_if
    sp.p[6] = (const float*)d_in[6]; // W_io
    sp.p[7] = (const float*)d_in[8]; // W_ig
    sp.p[8] = (const float*)d_in[9]; // W_y

    char* ws = (char*)d_ws;
    unsigned short* Whp = (unsigned short*)(ws + 0);          //  8 MB
    unsigned short* Wip = (unsigned short*)(ws + 8388608);    //  8 MB
    unsigned short* Wy  = (unsigned short*)(ws + 16777216);   //  2 MB
    unsigned short* xT  = (unsigned short*)(ws + 18874368);   // 64 MB
    unsigned short* h0  = (unsigned short*)(ws + 86245376);   // 128 KB
    unsigned short* h1  = (unsigned short*)(ws + 86376448);   // 128 KB
    int*            bar = (int*)(ws + 86507520);              // 4 B

    pack_weights<<<dim3(16, 16, 9), 256, 0, stream>>>(sp, Whp, Wip, Wy);
    convert_x<<<32768, 256, 0, stream>>>(x, xT);
    hipMemsetAsync(h0, 0, 64 * 1024 * 2, stream);
    hipMemsetAsync(bar, 0, 4, stream);

    lstm_seq<<<64, 512, 0, stream>>>(xT, Whp, Wip, h0, h1, bar);

    final_gemm<<<64, 256, 0, stream>>>(h0, Wy, (float*)d_out);
}